// Round 2
// baseline (168.565 us; speedup 1.0000x reference)
//
#include <hip/hip_runtime.h>
#include <cstdint>

typedef __attribute__((ext_vector_type(8))) short short8;
typedef __attribute__((ext_vector_type(4))) short short4x;
typedef __attribute__((ext_vector_type(4))) float floatx4;

__device__ __forceinline__ unsigned short f2b(float f) {
    unsigned int u = __builtin_bit_cast(unsigned int, f);
    u += 0x7fffu + ((u >> 16) & 1u);   // round-to-nearest-even
    return (unsigned short)(u >> 16);
}
__device__ __forceinline__ float b2f(unsigned short s) {
    unsigned int u = ((unsigned int)s) << 16;
    return __builtin_bit_cast(float, u);
}
__device__ __forceinline__ float fast_exp2(float x) {
    float r;
    asm("v_exp_f32 %0, %1" : "=v"(r) : "v"(x));
    return r;
}
// pack trunc-bf16(lo), trunc-bf16(hi) into one uint via v_perm_b32
__device__ __forceinline__ unsigned int pack_bf16_trunc(float lo, float hi) {
    return __builtin_amdgcn_perm(__builtin_bit_cast(unsigned int, hi),
                                 __builtin_bit_cast(unsigned int, lo), 0x07060302u);
}

#define GLDS(g, l) __builtin_amdgcn_global_load_lds(                                   \
    (const __attribute__((address_space(1))) unsigned int*)(g),                        \
    (__attribute__((address_space(3))) unsigned int*)(l), 16, 0, 0)

// ---------------- fused prep: x->bf16 cvt + both weight transposes ----------------
__global__ __launch_bounds__(256) void prep_kernel(const float* __restrict__ x,
                                                   unsigned short* __restrict__ xb,
                                                   const float* __restrict__ w1,
                                                   unsigned short* __restrict__ w1t,
                                                   const float* __restrict__ w2,
                                                   unsigned short* __restrict__ w2t) {
    __shared__ unsigned short tile[64][65];
    const int b = blockIdx.x, t = threadIdx.x;
    if (b < 1024) {
        for (int i = b * 256 + t; i < 1048576; i += 262144) {
            float4 v = ((const float4*)x)[i];
            ushort4 o;
            o.x = f2b(v.x); o.y = f2b(v.y); o.z = f2b(v.z); o.w = f2b(v.w);
            ((ushort4*)xb)[i] = o;
        }
        return;
    }
    const float* W; unsigned short* Wt; int K, N, kb, nb;
    if (b < 1792) { W = w1; Wt = w1t; K = 1024; N = 3072; kb = (b - 1024) & 15; nb = (b - 1024) >> 4; }
    else          { W = w2; Wt = w2t; K = 1024; N = 1024; kb = (b - 1792) & 15; nb = (b - 1792) >> 4; }
    const int k0 = kb * 64, n0 = nb * 64;
    for (int idx = t; idx < 64 * 64; idx += 256) {
        int i = idx >> 6, j = idx & 63;
        tile[j][i] = f2b(W[(size_t)(k0 + i) * N + n0 + j]);
    }
    __syncthreads();
    for (int idx = t; idx < 64 * 64; idx += 256) {
        int r = idx >> 6, c = idx & 63;
        Wt[(size_t)(n0 + r) * K + k0 + c] = tile[r][c];
    }
}

// ---------------- bf16 MFMA GEMM, 256x192 tile, 8-wave 4-phase counted-vmcnt ------
// M=4096 N=3072 K=1024 fixed. Grid (16,16) = 256 blocks = 1/CU.
// LDS 112 KB: As[2][256x64], Bs[2][192x64], XOR bank-swizzle (group ^= row&7) applied
// via pre-swizzled GLDS *source* (linear dest) + swizzled ds_read (both-sides rule).
// Per K-tile: 4 phases x {ds_read ; GLDS-issue ; [counted vmcnt] ; s_barrier ;
// lgkmcnt(0) ; setprio(1) ; 12 MFMA ; setprio(0) ; s_barrier}. vmcnt never 0 in loop.
// Staging chunks per tile: A13(kt+1)@ph0, B(kt+2)@ph1, A02(kt+2)@ph2.
// Derived waits: ph1 vmcnt(10) -> A13(kt) landed before ph2 reads chunks 1,3;
//                ph3 vmcnt(7)  -> B(kt+1)+A02(kt+1) landed before next ph0.
#define MFMA16(a_, b_, c_) __builtin_amdgcn_mfma_f32_16x16x32_bf16((a_), (b_), (c_), 0, 0, 0)

#define PH12(m0) do {                                              \
    acc[(m0)][0]     = MFMA16(a00, b00, acc[(m0)][0]);             \
    acc[(m0) + 1][0] = MFMA16(a10, b00, acc[(m0) + 1][0]);         \
    acc[(m0)][1]     = MFMA16(a00, b10, acc[(m0)][1]);             \
    acc[(m0) + 1][1] = MFMA16(a10, b10, acc[(m0) + 1][1]);         \
    acc[(m0)][2]     = MFMA16(a00, b20, acc[(m0)][2]);             \
    acc[(m0) + 1][2] = MFMA16(a10, b20, acc[(m0) + 1][2]);         \
    acc[(m0)][0]     = MFMA16(a01, b01, acc[(m0)][0]);             \
    acc[(m0) + 1][0] = MFMA16(a11, b01, acc[(m0) + 1][0]);         \
    acc[(m0)][1]     = MFMA16(a01, b11, acc[(m0)][1]);             \
    acc[(m0) + 1][1] = MFMA16(a11, b11, acc[(m0) + 1][1]);         \
    acc[(m0)][2]     = MFMA16(a01, b21, acc[(m0)][2]);             \
    acc[(m0) + 1][2] = MFMA16(a11, b21, acc[(m0) + 1][2]);         \
} while (0)

#define LDA(mi, kc) (*(const short8*)&As[buf][aRow + (mi) * 1024 + ((kc) ? g1 : g0)])
#define LDB(ni, kc) (*(const short8*)&Bs[buf][bRow + (ni) * 1024 + ((kc) ? g1 : g0)])

#define STAGE_A02(kt_) { const unsigned short* s_ = aSrc + (kt_) * 64;  \
    GLDS(s_,             &As[(kt_) & 1][ldsOff]);                       \
    GLDS(s_ + 128 * 1024, &As[(kt_) & 1][8192 + ldsOff]); }
#define STAGE_A13(kt_) { const unsigned short* s_ = aSrc + (kt_) * 64;  \
    GLDS(s_ + 64 * 1024,  &As[(kt_) & 1][4096 + ldsOff]);               \
    GLDS(s_ + 192 * 1024, &As[(kt_) & 1][12288 + ldsOff]); }
#define STAGE_B3(kt_) { const unsigned short* s_ = bSrc + (kt_) * 64;   \
    GLDS(s_,             &Bs[(kt_) & 1][ldsOff]);                       \
    GLDS(s_ + 64 * 1024,  &Bs[(kt_) & 1][4096 + ldsOff]);               \
    GLDS(s_ + 128 * 1024, &Bs[(kt_) & 1][8192 + ldsOff]); }

__global__ __launch_bounds__(512, 2) void gemm_bt_kernel(const unsigned short* __restrict__ A,
                                                         const unsigned short* __restrict__ Bt,
                                                         const float* __restrict__ bias,
                                                         unsigned short* __restrict__ C,
                                                         unsigned short* __restrict__ vTout,
                                                         int vSplit) {
    __shared__ unsigned short As[2][256 * 64];   // 64 KB
    __shared__ unsigned short Bs[2][192 * 64];   // 48 KB

    const int t = threadIdx.x;
    const int wave = t >> 6, lane = t & 63;
    const int quad = lane >> 4, l16 = lane & 15;
    const int wm = wave >> 2, wn = wave & 3;
    const int rowBase = blockIdx.x << 8;
    const int colBase = blockIdx.y * 192;

    floatx4 acc[8][3];
#pragma unroll
    for (int i = 0; i < 8; ++i)
#pragma unroll
        for (int j = 0; j < 3; ++j) acc[i][j] = (floatx4){0.f, 0.f, 0.f, 0.f};

    // staging: thread t -> row-in-chunk rr = t>>3, stored 16B-group = t&7,
    // source group = (t&7) ^ (rr&7); LDS dest linear = t*16 B (wave-uniform+lane*16)
    const int rr = t >> 3;
    const int gsrc = ((t & 7) ^ (rr & 7)) * 8;
    const unsigned short* aSrc = A + (size_t)(rowBase + rr) * 1024 + gsrc;
    const unsigned short* bSrc = Bt + (size_t)(colBase + rr) * 1024 + gsrc;
    const int ldsOff = t * 8;   // shorts

    // fragment reads: row = ...+l16, want group kc*4+quad -> stored group ^ (row&7)
    const int rg = l16 & 7;
    const int g0 = (quad ^ rg) * 8;
    const int g1 = g0 ^ 32;                    // ((4|quad)^rg)*8
    const int aRow = (wm * 128 + l16) * 64;
    const int bRow = (wn * 48 + l16) * 64;

    // prologue: B(0), A02(0), A13(0), B(1), A02(1) -> 12 outstanding
    STAGE_B3(0); STAGE_A02(0); STAGE_A13(0); STAGE_B3(1); STAGE_A02(1);
    asm volatile("s_waitcnt vmcnt(7)" ::: "memory");   // B(0)+A02(0) landed
    __builtin_amdgcn_s_barrier();

    for (int kt = 0; kt < 14; ++kt) {
        const int buf = kt & 1;
        short8 b00, b01, b10, b11, b20, b21;
#pragma unroll
        for (int p = 0; p < 4; ++p) {
            if (p == 0) {
                b00 = LDB(0, 0); b01 = LDB(0, 1);
                b10 = LDB(1, 0); b11 = LDB(1, 1);
                b20 = LDB(2, 0); b21 = LDB(2, 1);
            }
            short8 a00 = LDA(2 * p, 0),     a01 = LDA(2 * p, 1);
            short8 a10 = LDA(2 * p + 1, 0), a11 = LDA(2 * p + 1, 1);
            if (p == 0) STAGE_A13(kt + 1);
            if (p == 1) STAGE_B3(kt + 2);
            if (p == 2) STAGE_A02(kt + 2);
            if (p == 1) asm volatile("s_waitcnt vmcnt(10)" ::: "memory");
            if (p == 3) asm volatile("s_waitcnt vmcnt(7)" ::: "memory");
            __builtin_amdgcn_s_barrier();
            asm volatile("s_waitcnt lgkmcnt(0)" ::: "memory");
            __builtin_amdgcn_s_setprio(1);
            PH12(2 * p);
            __builtin_amdgcn_s_setprio(0);
            __builtin_amdgcn_s_barrier();
        }
    }

    // tail: stage last chunk, full drain once, compute tiles 14,15 barrier-free
    STAGE_A13(15);
    asm volatile("s_waitcnt vmcnt(0)" ::: "memory");
    __builtin_amdgcn_s_barrier();
#pragma unroll
    for (int kt2 = 14; kt2 < 16; ++kt2) {
        const int buf = kt2 & 1;
        short8 b00 = LDB(0, 0), b01 = LDB(0, 1);
        short8 b10 = LDB(1, 0), b11 = LDB(1, 1);
        short8 b20 = LDB(2, 0), b21 = LDB(2, 1);
#pragma unroll
        for (int m0 = 0; m0 < 8; m0 += 2) {
            short8 a00 = LDA(m0, 0),     a01 = LDA(m0, 1);
            short8 a10 = LDA(m0 + 1, 0), a11 = LDA(m0 + 1, 1);
            PH12(m0);
        }
    }

    // epilogue: per-fragment Q/K vs V split (boundary 2048 is 16-aligned)
#pragma unroll
    for (int mi = 0; mi < 8; ++mi) {
        const int row0 = rowBase + wm * 128 + mi * 16 + quad * 4;
#pragma unroll
        for (int ni = 0; ni < 3; ++ni) {
            const int colA = colBase + wn * 48 + ni * 16 + l16;
            const float bv = bias[colA];
            if (colA >= vSplit) {
                const int vcol = colA - vSplit;
#pragma unroll
                for (int r = 0; r < 4; ++r) {
                    const int row = row0 + r;
                    vTout[((size_t)((row >> 10) * 16 + (vcol >> 6)) * 64 + (vcol & 63)) * 1024
                          + (row & 1023)] = f2b(acc[mi][ni][r] + bv);
                }
            } else {
#pragma unroll
                for (int r = 0; r < 4; ++r) {
                    const int row = row0 + r;
                    C[(size_t)row * 3072 + colA] = f2b(acc[mi][ni][r] + bv);
                }
            }
        }
    }
}

// ---------------- fp32-out GEMM 128x64 tiles (grid 512, 2/CU), GLDS dbuf ----------------
__global__ __launch_bounds__(256) void gemm2_kernel(const unsigned short* __restrict__ A,
                                                    const unsigned short* __restrict__ Bt,
                                                    const float* __restrict__ bias,
                                                    float* __restrict__ C,
                                                    int M, int N, int K) {
    __shared__ unsigned short As[2][128][32];   // 16 KB
    __shared__ unsigned short Bs[2][64][32];    // 8 KB

    const int t = threadIdx.x;
    const int wave = t >> 6, lane = t & 63;
    const int quad = lane >> 4, l16 = lane & 15;
    const int rowBase = blockIdx.x * 128;
    const int colBase = blockIdx.y * 64;
    const int waveM = (wave >> 1) * 64;
    const int waveN = (wave & 1) * 32;

    floatx4 acc[4][2];
#pragma unroll
    for (int i = 0; i < 4; ++i)
#pragma unroll
        for (int j = 0; j < 2; ++j) acc[i][j] = (floatx4){0.f, 0.f, 0.f, 0.f};

    const int r0 = t >> 2, cc0 = (t & 3) * 8;
    const int r1 = 64 + (t >> 2);
    const unsigned short* aBase = A + (size_t)rowBase * K;
    const unsigned short* bBase = Bt + (size_t)colBase * K;

    auto stage = [&](int kk, int bf) {
        const int k0 = kk * 32;
        GLDS(aBase + (size_t)r0 * K + k0 + cc0, &As[bf][r0][cc0]);
        GLDS(aBase + (size_t)r1 * K + k0 + cc0, &As[bf][r1][cc0]);
        GLDS(bBase + (size_t)r0 * K + k0 + cc0, &Bs[bf][r0][cc0]);
    };

    const int nIter = K >> 5;
    stage(0, 0);

    for (int kk = 0; kk < nIter; ++kk) {
        __syncthreads();
        if (kk + 1 < nIter) stage(kk + 1, (kk + 1) & 1);
        const int buf = kk & 1;

        short8 af[4], bf[2];
#pragma unroll
        for (int mi = 0; mi < 4; ++mi)
            af[mi] = *(const short8*)&As[buf][waveM + mi * 16 + l16][quad * 8];
#pragma unroll
        for (int ni = 0; ni < 2; ++ni)
            bf[ni] = *(const short8*)&Bs[buf][waveN + ni * 16 + l16][quad * 8];
#pragma unroll
        for (int mi = 0; mi < 4; ++mi)
#pragma unroll
            for (int ni = 0; ni < 2; ++ni)
                acc[mi][ni] = __builtin_amdgcn_mfma_f32_16x16x32_bf16(af[mi], bf[ni], acc[mi][ni], 0, 0, 0);
    }

#pragma unroll
    for (int mi = 0; mi < 4; ++mi)
#pragma unroll
        for (int ni = 0; ni < 2; ++ni) {
            int col = colBase + waveN + ni * 16 + l16;
            float bv = bias[col];
#pragma unroll
            for (int r = 0; r < 4; ++r) {
                int row = rowBase + waveM + mi * 16 + quad * 4 + r;
                C[(size_t)row * N + col] = acc[mi][ni][r] + bv;
            }
        }
}

// ---------------- fused causal flash attention, 2 kv-tiles per barrier ----------------
// S^T = K.Q^T (A=K, B=Q); P^T register-resident; O^T = V^T.P^T. Paired q-tiles
// (p, 15-p) share the K/V stream. Two kv-tiles staged per barrier (32 KB window
// > HBM latency). exp via raw v_exp_f32; P packed via v_perm truncation.
__global__ __launch_bounds__(256) void attn_kernel(const unsigned short* __restrict__ qkv,
                                                   const unsigned short* __restrict__ vT,
                                                   unsigned short* __restrict__ aout) {
    __shared__ unsigned short Ks[2][2][4096];   // [buf][slot][kv*64+d swizzled]  32 KB
    __shared__ unsigned short Vs[2][2][4096];   // 32 KB
    __shared__ unsigned short Tb[4][16 * 72];   // 9 KB

    const int p  = blockIdx.x;
    const int bh = blockIdx.y;
    const int b = bh >> 4, h = bh & 15;
    const int qb1 = p, qb2 = 15 - p;
    const int t = threadIdx.x;
    const int wave = t >> 6, lane = t & 63;
    const int quad = lane >> 4, l16 = lane & 15;
    const int h7 = l16 & 7;

    const size_t rowB = (size_t)b * 1024;
    const size_t hoff = (size_t)h * 64;
    const int qA0 = qb1 * 64 + wave * 16;
    const int qB0 = qb2 * 64 + wave * 16;

    const float qscale = 0.125f * 1.44269504f;   // fold softmax scale + log2e into Q
    short8 qfA[2], qfB[2];
#pragma unroll
    for (int kc = 0; kc < 2; ++kc) {
        short8 qa = *(const short8*)(qkv + (rowB + qA0 + l16) * 3072 + hoff + kc * 32 + quad * 8);
        short8 qb = *(const short8*)(qkv + (rowB + qB0 + l16) * 3072 + hoff + kc * 32 + quad * 8);
#pragma unroll
        for (int e = 0; e < 8; ++e) {
            qa[e] = (short)f2b(b2f((unsigned short)qa[e]) * qscale);
            qb[e] = (short)f2b(b2f((unsigned short)qb[e]) * qscale);
        }
        qfA[kc] = qa; qfB[kc] = qb;
    }

    const int lr = lane >> 3;
    const int sc8 = (lane & 7) * 8;
    const int gc8 = ((lane & 7) ^ lr) * 8;
    const unsigned short* kSrc = qkv + rowB * 3072 + hoff + 1024;
    const unsigned short* vSrc = vT + (size_t)bh * 65536;

    auto stageT = [&](int kt, int bf, int sl) {
        const unsigned short* kp = kSrc + (size_t)kt * 64 * 3072;
        const unsigned short* vp = vSrc + kt * 64;
        int r0 = wave * 16 + lr, r1 = r0 + 8;
        GLDS(kp + (size_t)r0 * 3072 + gc8, &Ks[bf][sl][r0 * 64 + sc8]);
        GLDS(kp + (size_t)r1 * 3072 + gc8, &Ks[bf][sl][r1 * 64 + sc8]);
        GLDS(vp + (size_t)r0 * 1024 + gc8, &Vs[bf][sl][r0 * 64 + sc8]);
        GLDS(vp + (size_t)r1 * 1024 + gc8, &Vs[bf][sl][r1 * 64 + sc8]);
    };

    float lpA = 0.f, lpB = 0.f;
    floatx4 oA[4], oB[4];
#pragma unroll
    for (int ni = 0; ni < 4; ++ni) {
        oA[ni] = (floatx4){0.f, 0.f, 0.f, 0.f};
        oB[ni] = (floatx4){0.f, 0.f, 0.f, 0.f};
    }

    const int nT = qb2 + 1;            // 9..16 kv-tiles
    const int nP = (nT + 1) >> 1;      // barrier steps

    auto doTile = [&](int kt, const unsigned short* Kb, const unsigned short* Vb) {
        short8 kf[4][2];
#pragma unroll
        for (int jn = 0; jn < 4; ++jn)
#pragma unroll
            for (int kc = 0; kc < 2; ++kc)
                kf[jn][kc] = *(const short8*)&Kb[(jn * 16 + l16) * 64 + (((kc * 4 + quad) ^ h7) * 8)];
        short4x vf[4][4];
#pragma unroll
        for (int ni = 0; ni < 4; ++ni)
#pragma unroll
            for (int jb = 0; jb < 4; ++jb)
                vf[ni][jb] = *(const short4x*)&Vb[(ni * 16 + l16) * 64 +
                                                 (((jb * 2 + (quad >> 1)) ^ h7) * 8) + (quad & 1) * 4];

        auto qtile = [&](short8 (&qf)[2], floatx4 (&o)[4], float& lp, bool diag) {
            floatx4 s[4];
#pragma unroll
            for (int jn = 0; jn < 4; ++jn) s[jn] = (floatx4){0.f, 0.f, 0.f, 0.f};
#pragma unroll
            for (int jn = 0; jn < 4; ++jn)
#pragma unroll
                for (int kc = 0; kc < 2; ++kc)
                    s[jn] = __builtin_amdgcn_mfma_f32_16x16x32_bf16(kf[jn][kc], qf[kc], s[jn], 0, 0, 0);
            if (diag) {
                int ql = wave * 16 + l16;
#pragma unroll
                for (int jn = 0; jn < 4; ++jn)
#pragma unroll
                    for (int r = 0; r < 4; ++r)
                        if (jn * 16 + quad * 4 + r > ql) s[jn][r] = -1e30f;
            }
            short4x pb[4];
#pragma unroll
            for (int jb = 0; jb < 4; ++jb) {
                float pe0 = fast_exp2(s[jb][0]);
                float pe1 = fast_exp2(s[jb][1]);
                float pe2 = fast_exp2(s[jb][2]);
                float pe3 = fast_exp2(s[jb][3]);
                lp += (pe0 + pe1) + (pe2 + pe3);
                uint2 u;
                u.x = pack_bf16_trunc(pe0, pe1);
                u.y = pack_bf16_trunc(pe2, pe3);
                pb[jb] = __builtin_bit_cast(short4x, u);
            }
#pragma unroll
            for (int jb = 0; jb < 4; ++jb)
#pragma unroll
                for (int ni = 0; ni < 4; ++ni)
                    o[ni] = __builtin_amdgcn_mfma_f32_16x16x16bf16_1k(vf[ni][jb], pb[jb], o[ni], 0, 0, 0);
        };

        qtile(qfB, oB, lpB, kt == qb2);
        if (kt <= qb1) qtile(qfA, oA, lpA, kt == qb1);
    };

    stageT(0, 0, 0);
    stageT(1, 0, 1);                   // nT >= 9, always valid

    for (int pi = 0; pi < nP; ++pi) {
        __syncthreads();               // pair pi staged
        if (pi + 1 < nP) {             // prefetch next pair (in flight across 2-tile compute)
            stageT(2 * pi + 2, (pi + 1) & 1, 0);
            if (2 * pi + 3 < nT) stageT(2 * pi + 3, (pi + 1) & 1, 1);
        }
        const int bfI = pi & 1;
        doTile(2 * pi, &Ks[bfI][0][0], &Vs[bfI][0][0]);
        if (2 * pi + 1 < nT) doTile(2 * pi + 1, &Ks[bfI][1][0], &Vs[bfI][1][0]);
    }

    lpA += __shfl_xor(lpA, 16); lpA += __shfl_xor(lpA, 32);
    lpB += __shfl_xor(lpB, 16); lpB += __shfl_xor(lpB, 32);
    const float liA = 1.f / lpA, liB = 1.f / lpB;

    auto writeOut = [&](floatx4 (&o)[4], float li, int q0) {
#pragma unroll
        for (int ni = 0; ni < 4; ++ni)
#pragma unroll
            for (int r = 0; r < 4; ++r)
                Tb[wave][l16 * 72 + ni * 16 + quad * 4 + r] = f2b(o[ni][r] * li);
#pragma unroll
        for (int i = 0; i < 2; ++i) {
            int q = lane >> 2, c = (lane & 3) + 4 * i;
            short8 v = *(const short8*)&Tb[wave][q * 72 + c * 8];
            *(short8*)(aout + (rowB + q0 + q) * 1024 + hoff + c * 8) = v;
        }
    };
    writeOut(oA, liA, qA0);
    writeOut(oB, liB, qB0);
}

extern "C" void kernel_launch(void* const* d_in, const int* in_sizes, int n_in,
                              void* d_out, int out_size, void* d_ws, size_t ws_size,
                              hipStream_t stream) {
    const float* x  = (const float*)d_in[0];
    const float* w1 = (const float*)d_in[1];
    const float* b1 = (const float*)d_in[2];
    const float* w2 = (const float*)d_in[3];
    const float* b2 = (const float*)d_in[4];
    float* out = (float*)d_out;

    unsigned short* xb   = (unsigned short*)d_ws;              // 8 MB
    unsigned short* w1t  = xb  + (size_t)4096 * 1024;          // 6 MB  [3072,1024]
    unsigned short* w2t  = w1t + (size_t)3072 * 1024;          // 2 MB  [1024,1024]
    unsigned short* qkv  = w2t + (size_t)1024 * 1024;          // 24 MB [4096,3072] (V third unused)
    unsigned short* attn = qkv + (size_t)4096 * 3072;          // 8 MB  [4096,1024]
    unsigned short* vTb  = attn + (size_t)4096 * 1024;         // 8 MB  [64,64,1024]

    prep_kernel<<<2048, 256, 0, stream>>>(x, xb, w1, w1t, w2, w2t);
    gemm_bt_kernel<<<dim3(16, 16), 512, 0, stream>>>(xb, w1t, b1, qkv, vTb, 2048);
    attn_kernel<<<dim3(8, 64), 256, 0, stream>>>(qkv, vTb, attn);
    gemm2_kernel<<<dim3(32, 16), 256, 0, stream>>>(attn, w2t, b2, out, 4096, 1024, 1024);
}

// Round 3
// 165.305 us; speedup vs baseline: 1.0197x; 1.0197x over previous
//
#include <hip/hip_runtime.h>
#include <cstdint>

typedef __attribute__((ext_vector_type(8))) short short8;
typedef __attribute__((ext_vector_type(4))) short short4x;
typedef __attribute__((ext_vector_type(4))) float floatx4;

__device__ __forceinline__ unsigned short f2b(float f) {
    unsigned int u = __builtin_bit_cast(unsigned int, f);
    u += 0x7fffu + ((u >> 16) & 1u);   // round-to-nearest-even
    return (unsigned short)(u >> 16);
}
__device__ __forceinline__ float b2f(unsigned short s) {
    unsigned int u = ((unsigned int)s) << 16;
    return __builtin_bit_cast(float, u);
}
__device__ __forceinline__ float fast_exp2(float x) {
    float r;
    asm("v_exp_f32 %0, %1" : "=v"(r) : "v"(x));
    return r;
}
// pack trunc-bf16(lo), trunc-bf16(hi) into one uint via v_perm_b32
__device__ __forceinline__ unsigned int pack_bf16_trunc(float lo, float hi) {
    return __builtin_amdgcn_perm(__builtin_bit_cast(unsigned int, hi),
                                 __builtin_bit_cast(unsigned int, lo), 0x07060302u);
}

#define GLDS(g, l) __builtin_amdgcn_global_load_lds(                                   \
    (const __attribute__((address_space(1))) unsigned int*)(g),                        \
    (__attribute__((address_space(3))) unsigned int*)(l), 16, 0, 0)

// ---------------- fused prep: x->bf16 cvt + both weight transposes ----------------
__global__ __launch_bounds__(256) void prep_kernel(const float* __restrict__ x,
                                                   unsigned short* __restrict__ xb,
                                                   const float* __restrict__ w1,
                                                   unsigned short* __restrict__ w1t,
                                                   const float* __restrict__ w2,
                                                   unsigned short* __restrict__ w2t) {
    __shared__ unsigned short tile[64][65];
    const int b = blockIdx.x, t = threadIdx.x;
    if (b < 1024) {
        for (int i = b * 256 + t; i < 1048576; i += 262144) {
            float4 v = ((const float4*)x)[i];
            ushort4 o;
            o.x = f2b(v.x); o.y = f2b(v.y); o.z = f2b(v.z); o.w = f2b(v.w);
            ((ushort4*)xb)[i] = o;
        }
        return;
    }
    const float* W; unsigned short* Wt; int K, N, kb, nb;
    if (b < 1792) { W = w1; Wt = w1t; K = 1024; N = 3072; kb = (b - 1024) & 15; nb = (b - 1024) >> 4; }
    else          { W = w2; Wt = w2t; K = 1024; N = 1024; kb = (b - 1792) & 15; nb = (b - 1792) >> 4; }
    const int k0 = kb * 64, n0 = nb * 64;
    for (int idx = t; idx < 64 * 64; idx += 256) {
        int i = idx >> 6, j = idx & 63;
        tile[j][i] = f2b(W[(size_t)(k0 + i) * N + n0 + j]);
    }
    __syncthreads();
    for (int idx = t; idx < 64 * 64; idx += 256) {
        int r = idx >> 6, c = idx & 63;
        Wt[(size_t)(n0 + r) * K + k0 + c] = tile[r][c];
    }
}

// ---------------- bf16 MFMA GEMM, 256x192 tile, 8-wave 4-phase counted-vmcnt ------
// M=4096 N=3072 K=1024 fixed. Grid (16,16) = 256 blocks = 1/CU.
#define MFMA16(a_, b_, c_) __builtin_amdgcn_mfma_f32_16x16x32_bf16((a_), (b_), (c_), 0, 0, 0)

#define PH12(m0) do {                                              \
    acc[(m0)][0]     = MFMA16(a00, b00, acc[(m0)][0]);             \
    acc[(m0) + 1][0] = MFMA16(a10, b00, acc[(m0) + 1][0]);         \
    acc[(m0)][1]     = MFMA16(a00, b10, acc[(m0)][1]);             \
    acc[(m0) + 1][1] = MFMA16(a10, b10, acc[(m0) + 1][1]);         \
    acc[(m0)][2]     = MFMA16(a00, b20, acc[(m0)][2]);             \
    acc[(m0) + 1][2] = MFMA16(a10, b20, acc[(m0) + 1][2]);         \
    acc[(m0)][0]     = MFMA16(a01, b01, acc[(m0)][0]);             \
    acc[(m0) + 1][0] = MFMA16(a11, b01, acc[(m0) + 1][0]);         \
    acc[(m0)][1]     = MFMA16(a01, b11, acc[(m0)][1]);             \
    acc[(m0) + 1][1] = MFMA16(a11, b11, acc[(m0) + 1][1]);         \
    acc[(m0)][2]     = MFMA16(a01, b21, acc[(m0)][2]);             \
    acc[(m0) + 1][2] = MFMA16(a11, b21, acc[(m0) + 1][2]);         \
} while (0)

#define LDA(mi, kc) (*(const short8*)&As[buf][aRow + (mi) * 1024 + ((kc) ? g1 : g0)])
#define LDB(ni, kc) (*(const short8*)&Bs[buf][bRow + (ni) * 1024 + ((kc) ? g1 : g0)])

#define STAGE_A02(kt_) { const unsigned short* s_ = aSrc + (kt_) * 64;  \
    GLDS(s_,             &As[(kt_) & 1][ldsOff]);                       \
    GLDS(s_ + 128 * 1024, &As[(kt_) & 1][8192 + ldsOff]); }
#define STAGE_A13(kt_) { const unsigned short* s_ = aSrc + (kt_) * 64;  \
    GLDS(s_ + 64 * 1024,  &As[(kt_) & 1][4096 + ldsOff]);               \
    GLDS(s_ + 192 * 1024, &As[(kt_) & 1][12288 + ldsOff]); }
#define STAGE_B3(kt_) { const unsigned short* s_ = bSrc + (kt_) * 64;   \
    GLDS(s_,             &Bs[(kt_) & 1][ldsOff]);                       \
    GLDS(s_ + 64 * 1024,  &Bs[(kt_) & 1][4096 + ldsOff]);               \
    GLDS(s_ + 128 * 1024, &Bs[(kt_) & 1][8192 + ldsOff]); }

__global__ __launch_bounds__(512, 2) void gemm_bt_kernel(const unsigned short* __restrict__ A,
                                                         const unsigned short* __restrict__ Bt,
                                                         const float* __restrict__ bias,
                                                         unsigned short* __restrict__ C,
                                                         unsigned short* __restrict__ vTout,
                                                         int vSplit) {
    __shared__ unsigned short As[2][256 * 64];   // 64 KB
    __shared__ unsigned short Bs[2][192 * 64];   // 48 KB

    const int t = threadIdx.x;
    const int wave = t >> 6, lane = t & 63;
    const int quad = lane >> 4, l16 = lane & 15;
    const int wm = wave >> 2, wn = wave & 3;
    const int rowBase = blockIdx.x << 8;
    const int colBase = blockIdx.y * 192;

    floatx4 acc[8][3];
#pragma unroll
    for (int i = 0; i < 8; ++i)
#pragma unroll
        for (int j = 0; j < 3; ++j) acc[i][j] = (floatx4){0.f, 0.f, 0.f, 0.f};

    const int rr = t >> 3;
    const int gsrc = ((t & 7) ^ (rr & 7)) * 8;
    const unsigned short* aSrc = A + (size_t)(rowBase + rr) * 1024 + gsrc;
    const unsigned short* bSrc = Bt + (size_t)(colBase + rr) * 1024 + gsrc;
    const int ldsOff = t * 8;   // shorts

    const int rg = l16 & 7;
    const int g0 = (quad ^ rg) * 8;
    const int g1 = g0 ^ 32;
    const int aRow = (wm * 128 + l16) * 64;
    const int bRow = (wn * 48 + l16) * 64;

    STAGE_B3(0); STAGE_A02(0); STAGE_A13(0); STAGE_B3(1); STAGE_A02(1);
    asm volatile("s_waitcnt vmcnt(7)" ::: "memory");   // B(0)+A02(0) landed
    __builtin_amdgcn_s_barrier();

    for (int kt = 0; kt < 14; ++kt) {
        const int buf = kt & 1;
        short8 b00, b01, b10, b11, b20, b21;
#pragma unroll
        for (int p = 0; p < 4; ++p) {
            if (p == 0) {
                b00 = LDB(0, 0); b01 = LDB(0, 1);
                b10 = LDB(1, 0); b11 = LDB(1, 1);
                b20 = LDB(2, 0); b21 = LDB(2, 1);
            }
            short8 a00 = LDA(2 * p, 0),     a01 = LDA(2 * p, 1);
            short8 a10 = LDA(2 * p + 1, 0), a11 = LDA(2 * p + 1, 1);
            if (p == 0) STAGE_A13(kt + 1);
            if (p == 1) STAGE_B3(kt + 2);
            if (p == 2) STAGE_A02(kt + 2);
            if (p == 1) asm volatile("s_waitcnt vmcnt(10)" ::: "memory");
            if (p == 3) asm volatile("s_waitcnt vmcnt(7)" ::: "memory");
            __builtin_amdgcn_s_barrier();
            asm volatile("s_waitcnt lgkmcnt(0)" ::: "memory");
            __builtin_amdgcn_s_setprio(1);
            PH12(2 * p);
            __builtin_amdgcn_s_setprio(0);
            __builtin_amdgcn_s_barrier();
        }
    }

    STAGE_A13(15);
    asm volatile("s_waitcnt vmcnt(0)" ::: "memory");
    __builtin_amdgcn_s_barrier();
#pragma unroll
    for (int kt2 = 14; kt2 < 16; ++kt2) {
        const int buf = kt2 & 1;
        short8 b00 = LDB(0, 0), b01 = LDB(0, 1);
        short8 b10 = LDB(1, 0), b11 = LDB(1, 1);
        short8 b20 = LDB(2, 0), b21 = LDB(2, 1);
#pragma unroll
        for (int m0 = 0; m0 < 8; m0 += 2) {
            short8 a00 = LDA(m0, 0),     a01 = LDA(m0, 1);
            short8 a10 = LDA(m0 + 1, 0), a11 = LDA(m0 + 1, 1);
            PH12(m0);
        }
    }

#pragma unroll
    for (int mi = 0; mi < 8; ++mi) {
        const int row0 = rowBase + wm * 128 + mi * 16 + quad * 4;
#pragma unroll
        for (int ni = 0; ni < 3; ++ni) {
            const int colA = colBase + wn * 48 + ni * 16 + l16;
            const float bv = bias[colA];
            if (colA >= vSplit) {
                const int vcol = colA - vSplit;
#pragma unroll
                for (int r = 0; r < 4; ++r) {
                    const int row = row0 + r;
                    vTout[((size_t)((row >> 10) * 16 + (vcol >> 6)) * 64 + (vcol & 63)) * 1024
                          + (row & 1023)] = f2b(acc[mi][ni][r] + bv);
                }
            } else {
#pragma unroll
                for (int r = 0; r < 4; ++r) {
                    const int row = row0 + r;
                    C[(size_t)row * 3072 + colA] = f2b(acc[mi][ni][r] + bv);
                }
            }
        }
    }
}

// ---------------- gemm2: fp32-out GEMM, 128x128 tile, 8-wave, BK=64, GLDS dbuf ----
// M=4096 N=1024 K=1024 fixed. Grid (32,8) = 256 blocks = 1/CU. LDS 64 KB.
// Per K-tile: vmcnt(0) [own stage landed] ; s_barrier [all waves landed + done
// reading prev buf] ; issue STAGE(kt+1) into other buf ; ds_read 12 b128 ;
// lgkmcnt(0) ; 16 MFMA. One barrier + one vmcnt per tile; raw s_barrier so the
// compiler never force-drains vmcnt. Same XOR swizzle as gemm_bt (rule #21).
#define G2LDA(mi, kc) (*(const short8*)&As2[buf][aRow + (mi) * 1024 + ((kc) ? g1 : g0)])
#define G2LDB(ni, kc) (*(const short8*)&Bs2[buf][bRow + (ni) * 1024 + ((kc) ? g1 : g0)])
#define G2STAGE(kt_) { const unsigned short* sa_ = aSrc + (kt_) * 64;   \
    const unsigned short* sb_ = bSrc + (kt_) * 64;                      \
    GLDS(sa_,              &As2[(kt_) & 1][ldsOff]);                    \
    GLDS(sa_ + 64 * 1024,  &As2[(kt_) & 1][4096 + ldsOff]);             \
    GLDS(sb_,              &Bs2[(kt_) & 1][ldsOff]);                    \
    GLDS(sb_ + 64 * 1024,  &Bs2[(kt_) & 1][4096 + ldsOff]); }

__global__ __launch_bounds__(512, 2) void gemm2_kernel(const unsigned short* __restrict__ A,
                                                       const unsigned short* __restrict__ Bt,
                                                       const float* __restrict__ bias,
                                                       float* __restrict__ C) {
    __shared__ unsigned short As2[2][128 * 64];   // 32 KB
    __shared__ unsigned short Bs2[2][128 * 64];   // 32 KB

    const int t = threadIdx.x;
    const int wave = t >> 6, lane = t & 63;
    const int quad = lane >> 4, l16 = lane & 15;
    const int wm = wave >> 2, wn = wave & 3;       // 2M x 4N, wave tile 64x32
    const int rowBase = blockIdx.x << 7;
    const int colBase = blockIdx.y << 7;

    floatx4 acc[4][2];
#pragma unroll
    for (int i = 0; i < 4; ++i)
#pragma unroll
        for (int j = 0; j < 2; ++j) acc[i][j] = (floatx4){0.f, 0.f, 0.f, 0.f};

    const int rr = t >> 3;
    const int gsrc = ((t & 7) ^ (rr & 7)) * 8;
    const unsigned short* aSrc = A + (size_t)(rowBase + rr) * 1024 + gsrc;
    const unsigned short* bSrc = Bt + (size_t)(colBase + rr) * 1024 + gsrc;
    const int ldsOff = t * 8;   // shorts

    const int rg = l16 & 7;
    const int g0 = (quad ^ rg) * 8;
    const int g1 = g0 ^ 32;
    const int aRow = (wm * 64 + l16) * 64;
    const int bRow = (wn * 32 + l16) * 64;

    G2STAGE(0);

    for (int kt = 0; kt < 16; ++kt) {
        const int buf = kt & 1;
        asm volatile("s_waitcnt vmcnt(0)" ::: "memory");   // own stage(kt) landed
        __builtin_amdgcn_s_barrier();                      // all landed; prev-buf readers done
        if (kt + 1 < 16) G2STAGE(kt + 1);                  // into other buf: race-free

        short8 a0k0 = G2LDA(0, 0), a0k1 = G2LDA(0, 1);
        short8 a1k0 = G2LDA(1, 0), a1k1 = G2LDA(1, 1);
        short8 a2k0 = G2LDA(2, 0), a2k1 = G2LDA(2, 1);
        short8 a3k0 = G2LDA(3, 0), a3k1 = G2LDA(3, 1);
        short8 b0k0 = G2LDB(0, 0), b0k1 = G2LDB(0, 1);
        short8 b1k0 = G2LDB(1, 0), b1k1 = G2LDB(1, 1);
        asm volatile("s_waitcnt lgkmcnt(0)" ::: "memory");
        __builtin_amdgcn_sched_barrier(0);
        __builtin_amdgcn_s_setprio(1);
        acc[0][0] = MFMA16(a0k0, b0k0, acc[0][0]);
        acc[1][0] = MFMA16(a1k0, b0k0, acc[1][0]);
        acc[2][0] = MFMA16(a2k0, b0k0, acc[2][0]);
        acc[3][0] = MFMA16(a3k0, b0k0, acc[3][0]);
        acc[0][1] = MFMA16(a0k0, b1k0, acc[0][1]);
        acc[1][1] = MFMA16(a1k0, b1k0, acc[1][1]);
        acc[2][1] = MFMA16(a2k0, b1k0, acc[2][1]);
        acc[3][1] = MFMA16(a3k0, b1k0, acc[3][1]);
        acc[0][0] = MFMA16(a0k1, b0k1, acc[0][0]);
        acc[1][0] = MFMA16(a1k1, b0k1, acc[1][0]);
        acc[2][0] = MFMA16(a2k1, b0k1, acc[2][0]);
        acc[3][0] = MFMA16(a3k1, b0k1, acc[3][0]);
        acc[0][1] = MFMA16(a0k1, b1k1, acc[0][1]);
        acc[1][1] = MFMA16(a1k1, b1k1, acc[1][1]);
        acc[2][1] = MFMA16(a2k1, b1k1, acc[2][1]);
        acc[3][1] = MFMA16(a3k1, b1k1, acc[3][1]);
        __builtin_amdgcn_s_setprio(0);
    }

#pragma unroll
    for (int mi = 0; mi < 4; ++mi)
#pragma unroll
        for (int ni = 0; ni < 2; ++ni) {
            int col = colBase + wn * 32 + ni * 16 + l16;
            float bv = bias[col];
#pragma unroll
            for (int r = 0; r < 4; ++r) {
                int row = rowBase + wm * 64 + mi * 16 + quad * 4 + r;
                C[(size_t)row * 1024 + col] = acc[mi][ni][r] + bv;
            }
        }
}

// ---------------- fused causal flash attention, 2 kv-tiles per barrier ----------------
__global__ __launch_bounds__(256) void attn_kernel(const unsigned short* __restrict__ qkv,
                                                   const unsigned short* __restrict__ vT,
                                                   unsigned short* __restrict__ aout) {
    __shared__ unsigned short Ks[2][2][4096];   // [buf][slot][kv*64+d swizzled]  32 KB
    __shared__ unsigned short Vs[2][2][4096];   // 32 KB
    __shared__ unsigned short Tb[4][16 * 72];   // 9 KB

    const int p  = blockIdx.x;
    const int bh = blockIdx.y;
    const int b = bh >> 4, h = bh & 15;
    const int qb1 = p, qb2 = 15 - p;
    const int t = threadIdx.x;
    const int wave = t >> 6, lane = t & 63;
    const int quad = lane >> 4, l16 = lane & 15;
    const int h7 = l16 & 7;

    const size_t rowB = (size_t)b * 1024;
    const size_t hoff = (size_t)h * 64;
    const int qA0 = qb1 * 64 + wave * 16;
    const int qB0 = qb2 * 64 + wave * 16;

    const float qscale = 0.125f * 1.44269504f;   // fold softmax scale + log2e into Q
    short8 qfA[2], qfB[2];
#pragma unroll
    for (int kc = 0; kc < 2; ++kc) {
        short8 qa = *(const short8*)(qkv + (rowB + qA0 + l16) * 3072 + hoff + kc * 32 + quad * 8);
        short8 qb = *(const short8*)(qkv + (rowB + qB0 + l16) * 3072 + hoff + kc * 32 + quad * 8);
#pragma unroll
        for (int e = 0; e < 8; ++e) {
            qa[e] = (short)f2b(b2f((unsigned short)qa[e]) * qscale);
            qb[e] = (short)f2b(b2f((unsigned short)qb[e]) * qscale);
        }
        qfA[kc] = qa; qfB[kc] = qb;
    }

    const int lr = lane >> 3;
    const int sc8 = (lane & 7) * 8;
    const int gc8 = ((lane & 7) ^ lr) * 8;
    const unsigned short* kSrc = qkv + rowB * 3072 + hoff + 1024;
    const unsigned short* vSrc = vT + (size_t)bh * 65536;

    auto stageT = [&](int kt, int bf, int sl) {
        const unsigned short* kp = kSrc + (size_t)kt * 64 * 3072;
        const unsigned short* vp = vSrc + kt * 64;
        int r0 = wave * 16 + lr, r1 = r0 + 8;
        GLDS(kp + (size_t)r0 * 3072 + gc8, &Ks[bf][sl][r0 * 64 + sc8]);
        GLDS(kp + (size_t)r1 * 3072 + gc8, &Ks[bf][sl][r1 * 64 + sc8]);
        GLDS(vp + (size_t)r0 * 1024 + gc8, &Vs[bf][sl][r0 * 64 + sc8]);
        GLDS(vp + (size_t)r1 * 1024 + gc8, &Vs[bf][sl][r1 * 64 + sc8]);
    };

    float lpA = 0.f, lpB = 0.f;
    floatx4 oA[4], oB[4];
#pragma unroll
    for (int ni = 0; ni < 4; ++ni) {
        oA[ni] = (floatx4){0.f, 0.f, 0.f, 0.f};
        oB[ni] = (floatx4){0.f, 0.f, 0.f, 0.f};
    }

    const int nT = qb2 + 1;            // 9..16 kv-tiles
    const int nP = (nT + 1) >> 1;      // barrier steps

    auto doTile = [&](int kt, const unsigned short* Kb, const unsigned short* Vb) {
        short8 kf[4][2];
#pragma unroll
        for (int jn = 0; jn < 4; ++jn)
#pragma unroll
            for (int kc = 0; kc < 2; ++kc)
                kf[jn][kc] = *(const short8*)&Kb[(jn * 16 + l16) * 64 + (((kc * 4 + quad) ^ h7) * 8)];
        short4x vf[4][4];
#pragma unroll
        for (int ni = 0; ni < 4; ++ni)
#pragma unroll
            for (int jb = 0; jb < 4; ++jb)
                vf[ni][jb] = *(const short4x*)&Vb[(ni * 16 + l16) * 64 +
                                                 (((jb * 2 + (quad >> 1)) ^ h7) * 8) + (quad & 1) * 4];

        auto qtile = [&](short8 (&qf)[2], floatx4 (&o)[4], float& lp, bool diag) {
            floatx4 s[4];
#pragma unroll
            for (int jn = 0; jn < 4; ++jn) s[jn] = (floatx4){0.f, 0.f, 0.f, 0.f};
#pragma unroll
            for (int jn = 0; jn < 4; ++jn)
#pragma unroll
                for (int kc = 0; kc < 2; ++kc)
                    s[jn] = __builtin_amdgcn_mfma_f32_16x16x32_bf16(kf[jn][kc], qf[kc], s[jn], 0, 0, 0);
            if (diag) {
                int ql = wave * 16 + l16;
#pragma unroll
                for (int jn = 0; jn < 4; ++jn)
#pragma unroll
                    for (int r = 0; r < 4; ++r)
                        if (jn * 16 + quad * 4 + r > ql) s[jn][r] = -1e30f;
            }
            short4x pb[4];
#pragma unroll
            for (int jb = 0; jb < 4; ++jb) {
                float pe0 = fast_exp2(s[jb][0]);
                float pe1 = fast_exp2(s[jb][1]);
                float pe2 = fast_exp2(s[jb][2]);
                float pe3 = fast_exp2(s[jb][3]);
                lp += (pe0 + pe1) + (pe2 + pe3);
                uint2 u;
                u.x = pack_bf16_trunc(pe0, pe1);
                u.y = pack_bf16_trunc(pe2, pe3);
                pb[jb] = __builtin_bit_cast(short4x, u);
            }
#pragma unroll
            for (int jb = 0; jb < 4; ++jb)
#pragma unroll
                for (int ni = 0; ni < 4; ++ni)
                    o[ni] = __builtin_amdgcn_mfma_f32_16x16x16bf16_1k(vf[ni][jb], pb[jb], o[ni], 0, 0, 0);
        };

        qtile(qfB, oB, lpB, kt == qb2);
        if (kt <= qb1) qtile(qfA, oA, lpA, kt == qb1);
    };

    stageT(0, 0, 0);
    stageT(1, 0, 1);                   // nT >= 9, always valid

    for (int pi = 0; pi < nP; ++pi) {
        __syncthreads();               // pair pi staged
        if (pi + 1 < nP) {             // prefetch next pair (in flight across 2-tile compute)
            stageT(2 * pi + 2, (pi + 1) & 1, 0);
            if (2 * pi + 3 < nT) stageT(2 * pi + 3, (pi + 1) & 1, 1);
        }
        const int bfI = pi & 1;
        doTile(2 * pi, &Ks[bfI][0][0], &Vs[bfI][0][0]);
        if (2 * pi + 1 < nT) doTile(2 * pi + 1, &Ks[bfI][1][0], &Vs[bfI][1][0]);
    }

    lpA += __shfl_xor(lpA, 16); lpA += __shfl_xor(lpA, 32);
    lpB += __shfl_xor(lpB, 16); lpB += __shfl_xor(lpB, 32);
    const float liA = 1.f / lpA, liB = 1.f / lpB;

    auto writeOut = [&](floatx4 (&o)[4], float li, int q0) {
#pragma unroll
        for (int ni = 0; ni < 4; ++ni)
#pragma unroll
            for (int r = 0; r < 4; ++r)
                Tb[wave][l16 * 72 + ni * 16 + quad * 4 + r] = f2b(o[ni][r] * li);
#pragma unroll
        for (int i = 0; i < 2; ++i) {
            int q = lane >> 2, c = (lane & 3) + 4 * i;
            short8 v = *(const short8*)&Tb[wave][q * 72 + c * 8];
            *(short8*)(aout + (rowB + q0 + q) * 1024 + hoff + c * 8) = v;
        }
    };
    writeOut(oA, liA, qA0);
    writeOut(oB, liB, qB0);
}

extern "C" void kernel_launch(void* const* d_in, const int* in_sizes, int n_in,
                              void* d_out, int out_size, void* d_ws, size_t ws_size,
                              hipStream_t stream) {
    const float* x  = (const float*)d_in[0];
    const float* w1 = (const float*)d_in[1];
    const float* b1 = (const float*)d_in[2];
    const float* w2 = (const float*)d_in[3];
    const float* b2 = (const float*)d_in[4];
    float* out = (float*)d_out;

    unsigned short* xb   = (unsigned short*)d_ws;              // 8 MB
    unsigned short* w1t  = xb  + (size_t)4096 * 1024;          // 6 MB  [3072,1024]
    unsigned short* w2t  = w1t + (size_t)3072 * 1024;          // 2 MB  [1024,1024]
    unsigned short* qkv  = w2t + (size_t)1024 * 1024;          // 24 MB [4096,3072] (V third unused)
    unsigned short* attn = qkv + (size_t)4096 * 3072;          // 8 MB  [4096,1024]
    unsigned short* vTb  = attn + (size_t)4096 * 1024;         // 8 MB  [64,64,1024]

    prep_kernel<<<2048, 256, 0, stream>>>(x, xb, w1, w1t, w2, w2t);
    gemm_bt_kernel<<<dim3(16, 16), 512, 0, stream>>>(xb, w1t, b1, qkv, vTb, 2048);
    attn_kernel<<<dim3(8, 64), 256, 0, stream>>>(qkv, vTb, attn);
    gemm2_kernel<<<dim3(32, 8), 512, 0, stream>>>(attn, w2t, b2, out);
}